// Round 6
// baseline (136.782 us; speedup 1.0000x reference)
//
#include <hip/hip_runtime.h>
#include <math.h>

#define G      7
#define NBOX   98
#define CH     30
#define RAWF   1470
#define BATCH  8192

// Wave-internal LDS visibility: drain this wave's outstanding DS ops.
#define WAVE_SYNC() asm volatile("s_waitcnt lgkmcnt(0)" ::: "memory")

__device__ __forceinline__ float sigmoidf_(float x) {
    return 1.0f / (1.0f + expf(-x));
}
// Broadcast lane i's value to all lanes (i wave-uniform). Pure VALU, no LDS.
__device__ __forceinline__ float rdlanef(float x, int i) {
    return __int_as_float(__builtin_amdgcn_readlane(__float_as_int(x), i));
}
// Correctly-rounded x/7 (Markstein 2-fma refinement == IEEE x/7.0f here).
__device__ __forceinline__ float div7(float x) {
    const float r7 = 1.0f / 7.0f;
    float q0 = x * r7;
    float e  = fmaf(-7.0f, q0, x);
    return fmaf(e, r7, q0);
}

// Rare (~0.1%/batch) V in (64,98] greedy scan, one batch.
__device__ __forceinline__ void nms_slow(const float4* sbox, const float2* smeta,
                                         int V, int lane, float4 mb, float2 mm,
                                         float mlab, unsigned long long& k0,
                                         unsigned long long& k1) {
    const double UD = (double)0.3f + 0x1p-26;
    const int i2c = (lane + 64 < NBOX) ? lane + 64 : NBOX - 1;
    const float4 mb2 = sbox[i2c];
    const float2 mm2 = smeta[i2c];
    const float mlab2 = (lane + 64 < V) ? mm2.y : -1.0f;
    for (int i = 0; i < V; ++i) {
        float bx, by, bz, bw, ba, bl;
        if (i < 64) {
            bx = rdlanef(mb.x, i);  by = rdlanef(mb.y, i);
            bz = rdlanef(mb.z, i);  bw = rdlanef(mb.w, i);
            ba = rdlanef(mm.x, i);  bl = rdlanef(mlab, i);
        } else {
            bx = rdlanef(mb2.x, i - 64);  by = rdlanef(mb2.y, i - 64);
            bz = rdlanef(mb2.z, i - 64);  bw = rdlanef(mb2.w, i - 64);
            ba = rdlanef(mm2.x, i - 64);  bl = rdlanef(mlab2, i - 64);
        }
        float w1 = fmaxf(fminf(bz, mb.z) - fmaxf(bx, mb.x), 0.0f);
        float h1 = fmaxf(fminf(bw, mb.w) - fmaxf(by, mb.y), 0.0f);
        float i1 = w1 * h1;
        float u1 = fmaxf(ba + mm.x - i1, 1e-9f);
        bool hit1 = ((double)i1 > UD * (double)u1) && (bl == mlab);
        float w2 = fmaxf(fminf(bz, mb2.z) - fmaxf(bx, mb2.x), 0.0f);
        float h2 = fmaxf(fminf(bw, mb2.w) - fmaxf(by, mb2.y), 0.0f);
        float i2 = w2 * h2;
        float u2 = fmaxf(ba + mm2.x - i2, 1e-9f);
        bool hit2 = ((double)i2 > UD * (double)u2) && (bl == mlab2);
        unsigned long long row0 = __ballot(hit1);
        unsigned long long row1 = __ballot(hit2);
        if (((row0 & k0) | (row1 & k1)) == 0ull) {
            if (i < 64) k0 |= 1ull << i;
            else        k1 |= 1ull << (i - 64);
        }
    }
}

__global__ __launch_bounds__(128, 4) void yolo_nms_kernel(
    const float* __restrict__ p,
    float* __restrict__ out_boxes,   // [B,98,4]
    float* __restrict__ out_scores,  // [B,98]
    float* __restrict__ out_labels,  // [B,98]
    float* __restrict__ out_keep)    // [B,98]
{
#pragma clang fp contract(off)
    // Per-wave, per-batch sorted-box shuffle arrays (only LDS use).
    __shared__ __align__(16) float4 sboxS[2][2][NBOX];   // 6272 B
    __shared__ __align__(8)  float2 smetaS[2][2][NBOX];  // 3136 B

    const int lane = threadIdx.x & 63;
    const int wv   = threadIdx.x >> 6;
    const int b0   = (blockIdx.x * 2 + wv) * 2;   // this wave: batches b0, b0+1

    // -------- per-batch decode (two independent chains per wave) --------
    float4 bb[2][2]; float s[2][2], area[2][2], lblf[2][2];
    bool vld[2][2];
    float ms0[2], ms1[2];
    int V[2];

    #pragma unroll
    for (int u = 0; u < 2; ++u) {
        const int b = b0 + u;
        const float* base = p + (size_t)b * RAWF;

        // per-cell class argmax (once per cell, lanes 0..48)
        int labi = 0;
        if (lane < 49) {
            const float2* q2 = (const float2*)(base + lane * CH + 10);
            float2 c0 = q2[0];
            float best = c0.x; int bi = 0;
            if (c0.y > best) { best = c0.y; bi = 1; }
            #pragma unroll
            for (int k2 = 1; k2 < 10; ++k2) {
                float2 cv = q2[k2];
                if (cv.x > best) { best = cv.x; bi = 2 * k2; }
                if (cv.y > best) { best = cv.y; bi = 2 * k2 + 1; }
            }
            labi = bi + 1;
        }
        lblf[u][0] = (float)__builtin_amdgcn_ds_bpermute((lane >> 1) * 4, labi);
        lblf[u][1] = (float)__builtin_amdgcn_ds_bpermute((32 + (lane >> 1)) * 4, labi);

        #pragma unroll
        for (int sl = 0; sl < 2; ++sl) {
            const int t = lane + 64 * sl;
            s[u][sl] = -1.0f; vld[u][sl] = false; area[u][sl] = 0.0f;
            bb[u][sl] = make_float4(0.f, 0.f, 0.f, 0.f);
            if (t < NBOX) {
                const int cell = t >> 1, j = t & 1;
                const int r = cell / G, c = cell - r * G;
                const float* q = base + cell * CH + j * 4;
                float2 xy = *(const float2*)q;
                float2 wh = *(const float2*)(q + 2);
                float conf = base[cell * CH + 8 + j];
                float gx = div7(sigmoidf_(xy.x) + (float)c);
                float gy = div7(sigmoidf_(xy.y) + (float)r);
                float hx = wh.x * 0.5f, hy = wh.y * 0.5f;
                bb[u][sl] = make_float4(gx - hx, gy - hy, gx + hx, gy + hy);
                area[u][sl] = fmaxf(bb[u][sl].z - bb[u][sl].x, 0.0f) *
                              fmaxf(bb[u][sl].w - bb[u][sl].y, 0.0f);
                s[u][sl] = sigmoidf_(conf);
                vld[u][sl] = (s[u][sl] > 0.5f);
                ((float4*)(out_boxes + (size_t)b * (NBOX * 4)))[t] = bb[u][sl];
                out_scores[(size_t)b * NBOX + t] = s[u][sl];
                out_labels[(size_t)b * NBOX + t] = lblf[u][sl];
            }
        }
        V[u] = __popcll(__ballot(vld[u][0])) + __popcll(__ballot(vld[u][1]));
        ms0[u] = vld[u][0] ? s[u][0] : -1.0f;
        ms1[u] = vld[u][1] ? s[u][1] : -1.0f;
    }

    // -------- stable descending rank, both batches interleaved --------
    // loop1 candidates (orig idx 0..63) all precede lane+64 -> rk1 uses '>='.
    // loop2 candidates (orig idx 64..97) all exceed lane -> rk0 tie term vanishes.
    int rk0[2] = {0, 0}, rk1[2] = {0, 0};
    #pragma unroll 4
    for (int jj = 0; jj < 64; ++jj) {
        #pragma unroll
        for (int u = 0; u < 2; ++u) {
            float a = rdlanef(ms0[u], jj);
            rk0[u] += (a > ms0[u]) || ((a == ms0[u]) && (jj < lane));
            rk1[u] += (a >= ms1[u]);
        }
    }
    #pragma unroll 4
    for (int jj = 0; jj < 34; ++jj) {
        #pragma unroll
        for (int u = 0; u < 2; ++u) {
            float a = rdlanef(ms1[u], jj);
            rk0[u] += (a > ms0[u]);
            rk1[u] += (a > ms1[u]) || ((a == ms1[u]) && (jj < lane));
        }
    }

    // -------- push to sorted slots; pull slot 'lane' --------
    float4 mb[2]; float2 mm[2]; float mlab[2];
    #pragma unroll
    for (int u = 0; u < 2; ++u) {
        float4* sbox  = sboxS[wv][u];
        float2* smeta = smetaS[wv][u];
        if (vld[u][0]) { sbox[rk0[u]] = bb[u][0]; smeta[rk0[u]] = make_float2(area[u][0], lblf[u][0]); }
        if (vld[u][1]) { sbox[rk1[u]] = bb[u][1]; smeta[rk1[u]] = make_float2(area[u][1], lblf[u][1]); }
    }
    WAVE_SYNC();
    #pragma unroll
    for (int u = 0; u < 2; ++u) {
        mb[u] = sboxS[wv][u][lane];
        mm[u] = smetaS[wv][u][lane];
        mlab[u] = (lane < V[u]) ? mm[u].y : -1.0f;   // sentinel kills garbage hits
    }

    // -------- fused readlane-ballot NMS, both batches interleaved --------
    unsigned long long k0[2] = {0ull, 0ull}, k1[2] = {0ull, 0ull};
    const double UD = (double)0.3f + 0x1p-26;

#define ROW_HIT(U, I, HIT) do {                                              \
        float bx = rdlanef(mb[U].x, (I)), by = rdlanef(mb[U].y, (I));        \
        float bz = rdlanef(mb[U].z, (I)), bw = rdlanef(mb[U].w, (I));        \
        float ba = rdlanef(mm[U].x, (I)), bl = rdlanef(mlab[U], (I));        \
        float w = fmaxf(fminf(bz, mb[U].z) - fmaxf(bx, mb[U].x), 0.0f);      \
        float h = fmaxf(fminf(bw, mb[U].w) - fmaxf(by, mb[U].y), 0.0f);      \
        float inter = w * h;                                                 \
        float uc = fmaxf(ba + mm[U].x - inter, 1e-9f);                       \
        HIT = ((double)inter > UD * (double)uc) && (bl == mlab[U]);          \
    } while (0)

    if (V[0] <= 64 && V[1] <= 64) {
        const int Vm = (V[0] > V[1]) ? V[0] : V[1];
        int i = 0;
        for (; i + 2 <= Vm; i += 2) {       // 2 rows x 2 batches = 4 chains in flight
            bool hA0, hA1, hB0, hB1;
            ROW_HIT(0, i, hA0);
            ROW_HIT(1, i, hA1);
            ROW_HIT(0, i + 1, hB0);
            ROW_HIT(1, i + 1, hB1);
            unsigned long long rA0 = __ballot(hA0);
            unsigned long long rA1 = __ballot(hA1);
            unsigned long long rB0 = __ballot(hB0);
            unsigned long long rB1 = __ballot(hB1);
            if (i < V[0]     && (rA0 & k0[0]) == 0ull) k0[0] |= 1ull << i;
            if (i < V[1]     && (rA1 & k0[1]) == 0ull) k0[1] |= 1ull << i;
            if (i + 1 < V[0] && (rB0 & k0[0]) == 0ull) k0[0] |= 1ull << (i + 1);
            if (i + 1 < V[1] && (rB1 & k0[1]) == 0ull) k0[1] |= 1ull << (i + 1);
        }
        if (i < Vm) {
            bool hA0, hA1;
            ROW_HIT(0, i, hA0);
            ROW_HIT(1, i, hA1);
            unsigned long long rA0 = __ballot(hA0);
            unsigned long long rA1 = __ballot(hA1);
            if (i < V[0] && (rA0 & k0[0]) == 0ull) k0[0] |= 1ull << i;
            if (i < V[1] && (rA1 & k0[1]) == 0ull) k0[1] |= 1ull << i;
        }
    } else {
        nms_slow(sboxS[wv][0], smetaS[wv][0], V[0], lane, mb[0], mm[0], mlab[0], k0[0], k1[0]);
        nms_slow(sboxS[wv][1], smetaS[wv][1], V[1], lane, mb[1], mm[1], mlab[1], k0[1], k1[1]);
    }
#undef ROW_HIT

    // -------- keep: each lane knows its own ranks --------
    #pragma unroll
    for (int u = 0; u < 2; ++u) {
        const int b = b0 + u;
        float kv0 = 0.0f, kv1 = 0.0f;
        if (vld[u][0]) kv0 = (float)((((rk0[u] < 64) ? k0[u] : k1[u]) >> (rk0[u] & 63)) & 1ull);
        if (vld[u][1]) kv1 = (float)((((rk1[u] < 64) ? k0[u] : k1[u]) >> (rk1[u] & 63)) & 1ull);
        out_keep[(size_t)b * NBOX + lane] = kv0;
        if (lane + 64 < NBOX) out_keep[(size_t)b * NBOX + lane + 64] = kv1;
    }
}

extern "C" void kernel_launch(void* const* d_in, const int* in_sizes, int n_in,
                              void* d_out, int out_size, void* d_ws, size_t ws_size,
                              hipStream_t stream) {
    const float* p = (const float*)d_in[0];
    float* out = (float*)d_out;
    float* out_boxes  = out;
    float* out_scores = out + (size_t)BATCH * NBOX * 4;
    float* out_labels = out_scores + (size_t)BATCH * NBOX;
    float* out_keep   = out_labels + (size_t)BATCH * NBOX;

    yolo_nms_kernel<<<BATCH / 4, 128, 0, stream>>>(p, out_boxes, out_scores,
                                                   out_labels, out_keep);
}

// Round 7
// 119.979 us; speedup vs baseline: 1.1401x; 1.1401x over previous
//
#include <hip/hip_runtime.h>
#include <math.h>

#define G      7
#define NBOX   98
#define CH     30
#define RAWF   1470
#define BATCH  8192

// Wave-internal LDS visibility: drain this wave's outstanding DS ops.
#define WAVE_SYNC() asm volatile("s_waitcnt lgkmcnt(0)" ::: "memory")

__device__ __forceinline__ float sigmoidf_(float x) {
    return 1.0f / (1.0f + expf(-x));
}
// Broadcast lane i's value to all lanes (i wave-uniform). Pure VALU, no LDS.
__device__ __forceinline__ float rdlanef(float x, int i) {
    return __int_as_float(__builtin_amdgcn_readlane(__float_as_int(x), i));
}
// Correctly-rounded x/7 (Markstein 2-fma refinement == IEEE x/7.0f here).
__device__ __forceinline__ float div7(float x) {
    const float r7 = 1.0f / 7.0f;
    float q0 = x * r7;
    float e  = fmaf(-7.0f, q0, x);
    return fmaf(e, r7, q0);
}

// Rare (~0.1%/batch) V in (64,98] greedy scan, one batch (readlane variant).
__device__ __forceinline__ void nms_slow(const float4* sbox, const float2* smeta,
                                         int V, int lane, float4 mb, float2 mm,
                                         float mlab, unsigned long long& k0,
                                         unsigned long long& k1) {
    const double UD = (double)0.3f + 0x1p-26;
    const int i2c = (lane + 64 < NBOX) ? lane + 64 : NBOX - 1;
    const float4 mb2 = sbox[i2c];
    const float2 mm2 = smeta[i2c];
    const float mlab2 = (lane + 64 < V) ? mm2.y : -1.0f;
    for (int i = 0; i < V; ++i) {
        float bx, by, bz, bw, ba, bl;
        if (i < 64) {
            bx = rdlanef(mb.x, i);  by = rdlanef(mb.y, i);
            bz = rdlanef(mb.z, i);  bw = rdlanef(mb.w, i);
            ba = rdlanef(mm.x, i);  bl = rdlanef(mlab, i);
        } else {
            bx = rdlanef(mb2.x, i - 64);  by = rdlanef(mb2.y, i - 64);
            bz = rdlanef(mb2.z, i - 64);  bw = rdlanef(mb2.w, i - 64);
            ba = rdlanef(mm2.x, i - 64);  bl = rdlanef(mlab2, i - 64);
        }
        float w1 = fmaxf(fminf(bz, mb.z) - fmaxf(bx, mb.x), 0.0f);
        float h1 = fmaxf(fminf(bw, mb.w) - fmaxf(by, mb.y), 0.0f);
        float i1 = w1 * h1;
        float u1 = fmaxf(ba + mm.x - i1, 1e-9f);
        bool hit1 = ((double)i1 > UD * (double)u1) && (bl == mlab);
        float w2 = fmaxf(fminf(bz, mb2.z) - fmaxf(bx, mb2.x), 0.0f);
        float h2 = fmaxf(fminf(bw, mb2.w) - fmaxf(by, mb2.y), 0.0f);
        float i2 = w2 * h2;
        float u2 = fmaxf(ba + mm2.x - i2, 1e-9f);
        bool hit2 = ((double)i2 > UD * (double)u2) && (bl == mlab2);
        unsigned long long row0 = __ballot(hit1);
        unsigned long long row1 = __ballot(hit2);
        if (((row0 & k0) | (row1 & k1)) == 0ull) {
            if (i < 64) k0 |= 1ull << i;
            else        k1 |= 1ull << (i - 64);
        }
    }
}

__global__ __launch_bounds__(128, 8) void yolo_nms_kernel(
    const float* __restrict__ p,
    float* __restrict__ out_boxes,   // [B,98,4]
    float* __restrict__ out_scores,  // [B,98]
    float* __restrict__ out_labels,  // [B,98]
    float* __restrict__ out_keep)    // [B,98]
{
#pragma clang fp contract(off)
    // Per-wave LDS: sorted-box arrays + compacted scores.
    __shared__ __align__(16) float4 sboxS[2][NBOX];   // 3136 B
    __shared__ __align__(8)  float2 smetaS[2][NBOX];  // 1568 B (area, label)
    __shared__ __align__(16) float  cscS[2][104];     //  832 B

    const int lane = threadIdx.x & 63;
    const int wv   = threadIdx.x >> 6;
    const int b    = blockIdx.x * 2 + wv;

    float4* sbox  = sboxS[wv];
    float2* smeta = smetaS[wv];
    float*  csc   = cscS[wv];

    const float* base = p + (size_t)b * RAWF;

    // ---- per-cell class argmax (once per cell, lanes 0..48) ----
    int labi = 0;
    if (lane < 49) {
        const float2* q2 = (const float2*)(base + lane * CH + 10);  // 8B aligned
        float2 c0 = q2[0];
        float best = c0.x; int bi = 0;
        if (c0.y > best) { best = c0.y; bi = 1; }
        #pragma unroll
        for (int k2 = 1; k2 < 10; ++k2) {
            float2 cv = q2[k2];
            if (cv.x > best) { best = cv.x; bi = 2 * k2; }
            if (cv.y > best) { best = cv.y; bi = 2 * k2 + 1; }
        }
        labi = bi + 1;
    }
    // label of box t lives at cell t>>1; pull cross-lane (no LDS alloc).
    float lblf[2];
    lblf[0] = (float)__builtin_amdgcn_ds_bpermute((lane >> 1) * 4, labi);
    lblf[1] = (float)__builtin_amdgcn_ds_bpermute((32 + (lane >> 1)) * 4, labi);

    // ---- decode 2 slots per lane (t = lane, lane+64) ----
    float4 bb[2]; float s[2], area[2]; bool vld[2];
    #pragma unroll
    for (int u = 0; u < 2; ++u) {
        const int t = lane + 64 * u;
        s[u] = -1.0f; vld[u] = false; area[u] = 0.0f;
        bb[u] = make_float4(0.f, 0.f, 0.f, 0.f);
        if (t < NBOX) {
            const int cell = t >> 1, j = t & 1;
            const int r = cell / G, c = cell - r * G;
            const float* q = base + cell * CH + j * 4;
            float2 xy = *(const float2*)q;        // tx, ty (8B aligned)
            float2 wh = *(const float2*)(q + 2);  // tw, th
            float conf = base[cell * CH + 8 + j];
            float gx = div7(sigmoidf_(xy.x) + (float)c);
            float gy = div7(sigmoidf_(xy.y) + (float)r);
            float hx = wh.x * 0.5f, hy = wh.y * 0.5f;
            bb[u] = make_float4(gx - hx, gy - hy, gx + hx, gy + hy);
            area[u] = fmaxf(bb[u].z - bb[u].x, 0.0f) * fmaxf(bb[u].w - bb[u].y, 0.0f);
            s[u] = sigmoidf_(conf);
            vld[u] = (s[u] > 0.5f);
            ((float4*)(out_boxes + (size_t)b * (NBOX * 4)))[t] = bb[u];
            out_scores[(size_t)b * NBOX + t] = s[u];
            out_labels[(size_t)b * NBOX + t] = lblf[u];
        }
    }

    // ---- order-preserving ballot compaction of valid scores ----
    unsigned long long mk0 = __ballot(vld[0]);
    unsigned long long mk1 = __ballot(vld[1]);
    const int c0 = __popcll(mk0);
    const int V  = c0 + __popcll(mk1);           // valid = prefix of sorted order
    const unsigned long long below = (1ull << lane) - 1ull;
    const int ci0 = __popcll(mk0 & below);
    const int ci1 = c0 + __popcll(mk1 & below);
    if (vld[0]) csc[ci0] = s[0];
    if (vld[1]) csc[ci1] = s[1];
    WAVE_SYNC();

    // ---- stable descending rank via readlane over compact scores (V iters) ----
    const float scs  = csc[lane];
    const float scs2 = csc[(lane + 64 < 104) ? lane + 64 : 103];
    int rkA0 = 0, rkB0 = 0, rkA1 = 0, rkB1 = 0;   // partial sums (shorter chains)
    const int Vc = (V < 64) ? V : 64;
    int jj = 0;
    for (; jj + 2 <= Vc; jj += 2) {
        float sa = rdlanef(scs, jj);
        float sb = rdlanef(scs, jj + 1);
        rkA0 += (sa > s[0]) || ((sa == s[0]) && (jj < ci0));
        rkA1 += (sa > s[1]) || ((sa == s[1]) && (jj < ci1));
        rkB0 += (sb > s[0]) || ((sb == s[0]) && (jj + 1 < ci0));
        rkB1 += (sb > s[1]) || ((sb == s[1]) && (jj + 1 < ci1));
    }
    if (jj < Vc) {
        float sa = rdlanef(scs, jj);
        rkA0 += (sa > s[0]) || ((sa == s[0]) && (jj < ci0));
        rkA1 += (sa > s[1]) || ((sa == s[1]) && (jj < ci1));
    }
    for (int j2 = 64; j2 < V; ++j2) {            // rare: V > 64
        float sa = rdlanef(scs2, j2 - 64);
        rkA0 += (sa > s[0]) || ((sa == s[0]) && (j2 < ci0));
        rkA1 += (sa > s[1]) || ((sa == s[1]) && (j2 < ci1));
    }
    const int rk0 = rkA0 + rkB0;
    const int rk1 = rkA1 + rkB1;

    // ---- push boxes to sorted slots; pull own slot ----
    if (vld[0]) { sbox[rk0] = bb[0]; smeta[rk0] = make_float2(area[0], lblf[0]); }
    if (vld[1]) { sbox[rk1] = bb[1]; smeta[rk1] = make_float2(area[1], lblf[1]); }
    WAVE_SYNC();
    const float4 mb = sbox[lane];
    const float2 mm = smeta[lane];
    const float mlab = (lane < V) ? mm.y : -1.0f;   // sentinel kills garbage hits

    // ---- fused NMS: LDS-broadcast rows, 4-row unroll, ballot + SALU greedy ----
    unsigned long long k0 = 0ull, k1 = 0ull;
    // exact division-free predicate: RN(inter/uc) > 0.3f <=> inter > (0.3f+2^-26)*uc (exact f64)
    const double UD = (double)0.3f + 0x1p-26;

#define ROW_HIT_LDS(BI, MI, HIT) do {                                    \
        float w = fmaxf(fminf((BI).z, mb.z) - fmaxf((BI).x, mb.x), 0.0f);\
        float h = fmaxf(fminf((BI).w, mb.w) - fmaxf((BI).y, mb.y), 0.0f);\
        float inter = w * h;                                             \
        float uc = fmaxf((MI).x + mm.x - inter, 1e-9f);                  \
        HIT = ((double)inter > UD * (double)uc) && ((MI).y == mlab);     \
    } while (0)

    if (V <= 64) {
        int i = 0;
        for (; i + 4 <= V; i += 4) {     // 4 independent row chains in flight
            float4 bA = sbox[i],     bB = sbox[i + 1];
            float4 bC = sbox[i + 2], bD = sbox[i + 3];
            float2 mA = smeta[i],     mB = smeta[i + 1];
            float2 mC = smeta[i + 2], mD = smeta[i + 3];
            bool hA, hB, hC, hD;
            ROW_HIT_LDS(bA, mA, hA);
            ROW_HIT_LDS(bB, mB, hB);
            ROW_HIT_LDS(bC, mC, hC);
            ROW_HIT_LDS(bD, mD, hD);
            unsigned long long rA = __ballot(hA);
            unsigned long long rB = __ballot(hB);
            unsigned long long rC = __ballot(hC);
            unsigned long long rD = __ballot(hD);
            k0 |= ((rA & k0) == 0ull) ? (1ull << i) : 0ull;
            k0 |= ((rB & k0) == 0ull) ? (1ull << (i + 1)) : 0ull;
            k0 |= ((rC & k0) == 0ull) ? (1ull << (i + 2)) : 0ull;
            k0 |= ((rD & k0) == 0ull) ? (1ull << (i + 3)) : 0ull;
        }
        for (; i < V; ++i) {
            float4 bA = sbox[i];
            float2 mA = smeta[i];
            bool hA;
            ROW_HIT_LDS(bA, mA, hA);
            unsigned long long rA = __ballot(hA);
            k0 |= ((rA & k0) == 0ull) ? (1ull << i) : 0ull;
        }
    } else {
        nms_slow(sbox, smeta, V, lane, mb, mm, mlab, k0, k1);
    }
#undef ROW_HIT_LDS

    // ---- keep: lane knows its own ranks; no scatter needed ----
    float kv0 = 0.0f, kv1 = 0.0f;
    if (vld[0]) kv0 = (float)((((rk0 < 64) ? k0 : k1) >> (rk0 & 63)) & 1ull);
    if (vld[1]) kv1 = (float)((((rk1 < 64) ? k0 : k1) >> (rk1 & 63)) & 1ull);
    out_keep[(size_t)b * NBOX + lane] = kv0;
    if (lane + 64 < NBOX) out_keep[(size_t)b * NBOX + lane + 64] = kv1;
}

extern "C" void kernel_launch(void* const* d_in, const int* in_sizes, int n_in,
                              void* d_out, int out_size, void* d_ws, size_t ws_size,
                              hipStream_t stream) {
    const float* p = (const float*)d_in[0];
    float* out = (float*)d_out;
    float* out_boxes  = out;
    float* out_scores = out + (size_t)BATCH * NBOX * 4;
    float* out_labels = out_scores + (size_t)BATCH * NBOX;
    float* out_keep   = out_labels + (size_t)BATCH * NBOX;

    yolo_nms_kernel<<<BATCH / 2, 128, 0, stream>>>(p, out_boxes, out_scores,
                                                   out_labels, out_keep);
}